// Round 17
// baseline (195.405 us; speedup 1.0000x reference)
//
#include <hip/hip_runtime.h>

#define NB_HG 2048   // H*G = 32*64
#define DIM_N 128
#define DIM_D 128
#define DIM_S 256

// Numerics: golden = per-element strictly sequential ascending-d fp32 FMA over
// the SELECTED d's only (masked-out terms exact zeros). Verified bit-exact
// rounds 4-16. One block per hg: stage full X once, build din/dout lists,
// then two passes: inlier (8n x 16s per thread, ALL 256 s at once) and
// outlier (4n x 16s per thread). Chain per output unchanged: ascending
// selected d. LDS: Xt[d][n ^ 4*(d&7)] — SQ_LDS_BANK_CONFLICT=0 (r5-16).
// R16 post-mortem: LDS pipe (shared per CU) was ~94% loaded (2xb128+b32 per
// 64 FMA per wave) -> VALU starved at 60%. This round halves LDS-bytes/FMA.

__global__ void transpose_proj_kernel(const float* __restrict__ proj,
                                      float* __restrict__ projT)
{
    const int d = blockIdx.x;                      // 128
    const int s = threadIdx.x;                     // 256
    projT[d * DIM_S + s] = proj[s * DIM_D + d];    // coalesced write
}

template<bool TP>
__global__ __launch_bounds__(256, 2)   // min 2 waves/SIMD -> VGPR cap 256 (no spill)
void qjl_sketch_kernel(const float* __restrict__ data,
                       const float* __restrict__ mask,
                       const float* __restrict__ pmat,   // TP ? projT[d][s] : proj[s][d]
                       int* __restrict__ out)
{
    __shared__ float Xt[DIM_D * DIM_N];            // 64 KB: full X tile, swizzled
    __shared__ int   din[DIM_D];                   // inlier d's, ascending
    __shared__ int   dout[DIM_D];                  // outlier d's, ascending
    __shared__ int   win[2];                       // per-wave inlier counts

    const int hg  = blockIdx.x;
    const int tid = threadIdx.x;

    // ---------- build both compacted ascending d-lists ----------
    const int  lane = tid & 63;
    const int  w    = tid >> 6;
    bool is_in = false; int rank_in = 0;
    if (tid < 128) {                               // waves 0,1 only (whole waves)
        const float m = mask[hg * DIM_D + tid];    // exactly 0.0f or 1.0f
        is_in = (m == 0.0f);
        const unsigned long long bal = __ballot(is_in);
        if (lane == 0) win[w] = __popcll(bal);
        rank_in = __popcll(bal & ((1ull << lane) - 1ull));
    }
    __syncthreads();
    const int Kin = win[0] + win[1];               // uniform across block
    if (tid < 128) {
        if (is_in) din [rank_in          + (w ? win[0]        : 0)] = tid;
        else       dout[(lane - rank_in) + (w ? (64 - win[0]) : 0)] = tid;
    }

    // ---------- stage FULL X tile, transposed + swizzled ----------
    {
        const int d  = tid & 127;
        const int nh = tid >> 7;                   // 0 or 1
        const float* Xs = data + (size_t)hg * (DIM_N * DIM_D) + d;
        const int pcs = 4 * (d & 7);
        float* row = &Xt[d * DIM_N];
        #pragma unroll
        for (int g = 0; g < 16; ++g) {
            const int n0 = g * 8 + nh * 4;         // 4-aligned logical n block
            float4 v;
            v.x = Xs[(size_t)(n0 + 0) * DIM_D];    // coalesced: lanes span d
            v.y = Xs[(size_t)(n0 + 1) * DIM_D];
            v.z = Xs[(size_t)(n0 + 2) * DIM_D];
            v.w = Xs[(size_t)(n0 + 3) * DIM_D];
            *reinterpret_cast<float4*>(&row[n0 ^ pcs]) = v;
        }
    }
    __syncthreads();                               // lists + tile ready; last barrier

    const size_t inl_total = (size_t)NB_HG * DIM_N * 32;   // 8388608
    const size_t orow = (size_t)hg * DIM_N;

    // ================= inlier pass: 8n x 16s per thread, all 256 s =========
    {
        const int tn = tid & 15;                   // 16 n-groups (8 n each)
        const int ts = tid >> 4;                   // 16 s-groups (16 s each)
        const int C0 = 4 * tn;
        const int sb = 16 * ts;                    // s base for this thread

        float acc[16][8];                          // [j: s][i: n-slot] = 128 VGPR
        #pragma unroll
        for (int j = 0; j < 16; ++j)
            #pragma unroll
            for (int i = 0; i < 8; ++i) acc[j][i] = 0.0f;

        #pragma unroll 2
        for (int ci = 0; ci < Kin; ++ci) {         // ascending selected d
            const int dl = din[ci];                // uniform LDS broadcast
            float bv[16];
            if (TP) {
                const float* pr = pmat + (size_t)dl * DIM_S + sb;
                const float4 b0 = *reinterpret_cast<const float4*>(pr);
                const float4 b1 = *reinterpret_cast<const float4*>(pr + 4);
                const float4 b2 = *reinterpret_cast<const float4*>(pr + 8);
                const float4 b3 = *reinterpret_cast<const float4*>(pr + 12);
                bv[0]=b0.x; bv[1]=b0.y; bv[2]=b0.z; bv[3]=b0.w;
                bv[4]=b1.x; bv[5]=b1.y; bv[6]=b1.z; bv[7]=b1.w;
                bv[8]=b2.x; bv[9]=b2.y; bv[10]=b2.z; bv[11]=b2.w;
                bv[12]=b3.x; bv[13]=b3.y; bv[14]=b3.z; bv[15]=b3.w;
            } else {
                #pragma unroll
                for (int jj = 0; jj < 16; ++jj)
                    bv[jj] = pmat[(size_t)(sb + jj) * DIM_D + dl];
            }
            const int pcs = 4 * (dl & 7);
            const int P   = C0 ^ pcs;
            const float* r = &Xt[dl * DIM_N + P];
            const float4 q0 = *reinterpret_cast<const float4*>(r);        // n=C0..+3
            const float4 q1 = *reinterpret_cast<const float4*>(r + 64);   // n=64+C0..

            #pragma unroll
            for (int j = 0; j < 16; ++j) {
                acc[j][0] = fmaf(bv[j], q0.x, acc[j][0]);   // serial dep: order fixed
                acc[j][1] = fmaf(bv[j], q0.y, acc[j][1]);
                acc[j][2] = fmaf(bv[j], q0.z, acc[j][2]);
                acc[j][3] = fmaf(bv[j], q0.w, acc[j][3]);
                acc[j][4] = fmaf(bv[j], q1.x, acc[j][4]);
                acc[j][5] = fmaf(bv[j], q1.y, acc[j][5]);
                acc[j][6] = fmaf(bv[j], q1.z, acc[j][6]);
                acc[j][7] = fmaf(bv[j], q1.w, acc[j][7]);
            }
        }

        // sign-pack: two bytes per n (s = 16*ts+j; byte 2ts: j<8, byte 2ts+1: j>=8)
        #pragma unroll
        for (int i = 0; i < 8; ++i) {
            int b0 = 0, b1 = 0;
            #pragma unroll
            for (int j = 0; j < 8; ++j) {
                if (acc[j][i]     > 0.0f) b0 |= (1 << j);
                if (acc[j + 8][i] > 0.0f) b1 |= (1 << j);
            }
            const int n = (i < 4) ? (C0 + i) : (64 + C0 + (i - 4));
            const size_t base = (orow + n) * 32 + 2 * ts;
            out[base]     = b0;
            out[base + 1] = b1;
        }
    }

    // ================= outlier pass: 4n x 16s per thread, s 0..127 =========
    {
        const int Kout = DIM_D - Kin;
        const int tn2 = tid & 31;                  // 32 n-groups (4 n each)
        const int ts2 = tid >> 5;                  // 8 s-groups (16 s each)
        const int C0o = 4 * tn2;
        const int sb2 = 16 * ts2;

        float acc[16][4];                          // 64 VGPR
        #pragma unroll
        for (int j = 0; j < 16; ++j)
            #pragma unroll
            for (int i = 0; i < 4; ++i) acc[j][i] = 0.0f;

        #pragma unroll 2
        for (int ci = 0; ci < Kout; ++ci) {        // ascending selected d
            const int dl = dout[ci];               // uniform LDS broadcast
            float bv[16];
            if (TP) {
                const float* pr = pmat + (size_t)dl * DIM_S + sb2;
                const float4 b0 = *reinterpret_cast<const float4*>(pr);
                const float4 b1 = *reinterpret_cast<const float4*>(pr + 4);
                const float4 b2 = *reinterpret_cast<const float4*>(pr + 8);
                const float4 b3 = *reinterpret_cast<const float4*>(pr + 12);
                bv[0]=b0.x; bv[1]=b0.y; bv[2]=b0.z; bv[3]=b0.w;
                bv[4]=b1.x; bv[5]=b1.y; bv[6]=b1.z; bv[7]=b1.w;
                bv[8]=b2.x; bv[9]=b2.y; bv[10]=b2.z; bv[11]=b2.w;
                bv[12]=b3.x; bv[13]=b3.y; bv[14]=b3.z; bv[15]=b3.w;
            } else {
                #pragma unroll
                for (int jj = 0; jj < 16; ++jj)
                    bv[jj] = pmat[(size_t)(sb2 + jj) * DIM_D + dl];
            }
            const int pcs = 4 * (dl & 7);
            const int P   = C0o ^ pcs;
            const float4 q0 = *reinterpret_cast<const float4*>(&Xt[dl * DIM_N + P]);

            #pragma unroll
            for (int j = 0; j < 16; ++j) {
                acc[j][0] = fmaf(bv[j], q0.x, acc[j][0]);   // serial dep: order fixed
                acc[j][1] = fmaf(bv[j], q0.y, acc[j][1]);
                acc[j][2] = fmaf(bv[j], q0.z, acc[j][2]);
                acc[j][3] = fmaf(bv[j], q0.w, acc[j][3]);
            }
        }

        #pragma unroll
        for (int i = 0; i < 4; ++i) {
            int b0 = 0, b1 = 0;
            #pragma unroll
            for (int j = 0; j < 8; ++j) {
                if (acc[j][i]     > 0.0f) b0 |= (1 << j);
                if (acc[j + 8][i] > 0.0f) b1 |= (1 << j);
            }
            const int n = C0o + i;
            const size_t base = inl_total + (orow + n) * 16 + 2 * ts2;
            out[base]     = b0;
            out[base + 1] = b1;
        }
    }
}

extern "C" void kernel_launch(void* const* d_in, const int* in_sizes, int n_in,
                              void* d_out, int out_size, void* d_ws, size_t ws_size,
                              hipStream_t stream) {
    const float* data = (const float*)d_in[0];   // (1,32,64,128,128) fp32
    const float* mask = (const float*)d_in[1];   // (1,32,64,128) fp32, values {0,1}
    const float* proj = (const float*)d_in[2];   // (256,128) fp32
    int* out = (int*)d_out;                      // 8388608 inlier + 4194304 outlier int32

    const size_t tp_bytes = (size_t)DIM_D * DIM_S * sizeof(float);   // 128 KB
    if (ws_size >= tp_bytes) {
        float* projT = (float*)d_ws;
        transpose_proj_kernel<<<DIM_D, DIM_S, 0, stream>>>(proj, projT);
        qjl_sketch_kernel<true><<<NB_HG, 256, 0, stream>>>(data, mask, projT, out);
    } else {
        qjl_sketch_kernel<false><<<NB_HG, 256, 0, stream>>>(data, mask, proj, out);
    }
}